// Round 3
// baseline (441.625 us; speedup 1.0000x reference)
//
#include <hip/hip_runtime.h>

// B=4096, S=50, D=32, H=4, HD=8 ; one block per batch, weights in VGPRs, acts in LDS.
#define NB 4096
constexpr float kScale = 0.35355339059327378f; // 1/sqrt(8)

// LDS layout (floats):
constexpr int OFF_MW = 0;      // 104: 100 packed mask words + flag word at +100
constexpr int OFF_U  = 104;    // 4800: rawQ[0,1600) | rawK[1600,3200)->q | rawV[3200,4800)->ctx
constexpr int OFF_T  = 4904;   // 1600: tmp (first-projection result, [s][32])
constexpr int OFF_K2 = 6504;   // 1600: K heads [h][s][8]
constexpr int OFF_V2 = 8104;   // 1600: V heads [h][s][8]
constexpr int S_LEN  = 9704;   // 38,816 B -> 4 blocks/CU (16 waves)

__device__ __forceinline__ void load_wcol(const float* __restrict__ Wg, int d, float w[32]) {
  #pragma unroll
  for (int j = 0; j < 32; ++j) w[j] = Wg[j*32 + d];   // coalesced: lanes 0-31 contiguous
}

// dst = src @ W + b (W column in regs). Thread (d=t&31, s0=t>>5) does rows s0+8*ss.
// src reads: <=4 distinct addrs per wave (broadcast, conflict-free).
template<bool HEADS>
__device__ __forceinline__ void proj_pass(float* S, int src_off, const float w[32],
                                          float bias, int dst_off, float scale, int t) {
  const int d = t & 31, s0 = t >> 5;
  float acc[7];
  #pragma unroll
  for (int ss = 0; ss < 7; ++ss) acc[ss] = bias;
  #pragma unroll
  for (int kb = 0; kb < 32; kb += 4) {
    #pragma unroll
    for (int ss = 0; ss < 7; ++ss) {
      const int s = s0 + ss*8;
      if (s < 50) {
        const float4 x = *(const float4*)&S[src_off + s*32 + kb];
        acc[ss] = fmaf(x.x, w[kb+0], fmaf(x.y, w[kb+1],
                  fmaf(x.z, w[kb+2], fmaf(x.w, w[kb+3], acc[ss]))));
      }
    }
  }
  const int h = d >> 3, hd = d & 7;
  #pragma unroll
  for (int ss = 0; ss < 7; ++ss) {
    const int s = s0 + ss*8;
    if (s < 50) {
      const float v = acc[ss] * scale;
      if (HEADS) S[dst_off + h*400 + s*8 + hd] = v;   // 2-way bank alias = free
      else       S[dst_off + s*32 + d] = v;
    }
  }
}

__global__ __launch_bounds__(256, 4) void mha(
    const float* __restrict__ Qg, const float* __restrict__ Kg,
    const float* __restrict__ Vg, const void* __restrict__ maskg,
    const float* __restrict__ WQg, const float* __restrict__ bQg,
    const float* __restrict__ WKg, const float* __restrict__ bKg,
    const float* __restrict__ WVg, const float* __restrict__ bVg,
    const float* __restrict__ WOg, const float* __restrict__ bOg,
    float* __restrict__ outg)
{
  __shared__ __align__(16) float S[S_LEN];
  const int t = threadIdx.x;
  const int b = blockIdx.x;
  const int d = t & 31;

  // ---- A: stage raw Q/K/V, detect mask width, load K-weights + biases to regs ----
  float wk[32];
  load_wcol(WKg, d, wk);
  const float bq = bQg[d], bk = bKg[d], bv = bVg[d], bo = bOg[d];
  {
    const float4* q4 = (const float4*)Qg;
    const float4* k4 = (const float4*)Kg;
    const float4* v4 = (const float4*)Vg;
    float4* dU = (float4*)&S[OFF_U];
    #pragma unroll
    for (int it = 0; it < 5; ++it) {
      int idx = t + it*256;
      if (idx < 1200) {
        int m = idx / 400, e = idx - m*400;
        const float4* src = (m == 0) ? q4 : (m == 1) ? k4 : v4;
        dU[m*400 + e] = src[b*400 + e];
      }
    }
    if (t < 64) {   // wave 0: detect int32 vs byte mask
      const unsigned w = ((const unsigned*)maskg)[t];
      const unsigned long long ball = __ballot(w > 1u);
      if (t == 0) ((unsigned*)S)[OFF_MW + 100] = (ball != 0ull) ? 1u : 0u;
    }
  }
  __syncthreads();

  // ---- B: bit-pack mask (t<100) + first projection of K ----
  {
    const unsigned flag = ((const unsigned*)S)[OFF_MW + 100];
    if (t < 100) {
      const int i = t >> 1, half = t & 1;
      const int base = b*2500 + i*50 + half*32;
      const int cnt = half ? 18 : 32;
      unsigned w = 0;
      if (flag) {
        const unsigned char* mp = (const unsigned char*)maskg + base;
        for (int e = 0; e < cnt; ++e) w |= (mp[e] != 0) ? (1u << e) : 0u;
      } else {
        const int* mp = (const int*)maskg + base;
        for (int e = 0; e < cnt; ++e) w |= (mp[e] != 0) ? (1u << e) : 0u;
      }
      ((unsigned*)S)[OFF_MW + t] = w;
    }
  }
  proj_pass<false>(S, OFF_U + 1600, wk, bk, OFF_T, 1.f, t);
  __syncthreads();

  // ---- C: second projection of K -> head layout; prefetch V-weights ----
  float wv[32];
  load_wcol(WVg, d, wv);
  proj_pass<true>(S, OFF_T, wk, bk, OFF_K2, 1.f, t);
  __syncthreads();

  // ---- D: first projection of V ----
  proj_pass<false>(S, OFF_U + 3200, wv, bv, OFF_T, 1.f, t);
  __syncthreads();

  // ---- E: second projection of V; prefetch Q-weights ----
  float wq[32];
  load_wcol(WQg, d, wq);
  proj_pass<true>(S, OFF_T, wv, bv, OFF_V2, 1.f, t);
  __syncthreads();

  // ---- F: first projection of Q ----
  proj_pass<false>(S, OFF_U, wq, bq, OFF_T, 1.f, t);
  __syncthreads();

  // ---- G: second projection of Q -> q (pre-scaled) into dead rawK region ----
  proj_pass<true>(S, OFF_T, wq, bq, OFF_U + 1600, kScale, t);
  __syncthreads();

  // ---- H: attention; thread = (head, query row); ctx -> dead rawV region ----
  if (t < 200) {
    const int h = t / 50, i = t - h*50;
    const float* qh = &S[OFF_U + 1600 + h*400];
    const float* kh = &S[OFF_K2 + h*400];
    const float* vh = &S[OFF_V2 + h*400];
    float qr[8];
    {
      const float4 q0 = *(const float4*)&qh[i*8];
      const float4 q1 = *(const float4*)&qh[i*8 + 4];
      qr[0]=q0.x; qr[1]=q0.y; qr[2]=q0.z; qr[3]=q0.w;
      qr[4]=q1.x; qr[5]=q1.y; qr[6]=q1.z; qr[7]=q1.w;
    }
    const unsigned mw0 = ((const unsigned*)S)[OFF_MW + i*2];
    const unsigned mw1 = ((const unsigned*)S)[OFF_MW + i*2 + 1];
    float sb[50];
    float mx = -__builtin_inff();
    #pragma unroll
    for (int j = 0; j < 50; ++j) {
      const float4 k0 = *(const float4*)&kh[j*8];
      const float4 k1 = *(const float4*)&kh[j*8 + 4];
      float s =        qr[0]*k0.x;
      s = fmaf(qr[1], k0.y, s);
      s = fmaf(qr[2], k0.z, s);
      s = fmaf(qr[3], k0.w, s);
      s = fmaf(qr[4], k1.x, s);
      s = fmaf(qr[5], k1.y, s);
      s = fmaf(qr[6], k1.z, s);
      s = fmaf(qr[7], k1.w, s);
      const unsigned bit = (j < 32) ? ((mw0 >> j) & 1u) : ((mw1 >> (j-32)) & 1u);
      s = bit ? -__builtin_inff() : s;
      sb[j] = s;
      mx = fmaxf(mx, s);
    }
    float sum = 0.f;
    float acc[8] = {0,0,0,0,0,0,0,0};
    #pragma unroll
    for (int j = 0; j < 50; ++j) {
      const float p = __expf(sb[j] - mx);
      sum += p;
      const float4 v0 = *(const float4*)&vh[j*8];
      const float4 v1 = *(const float4*)&vh[j*8 + 4];
      acc[0] = fmaf(p, v0.x, acc[0]);
      acc[1] = fmaf(p, v0.y, acc[1]);
      acc[2] = fmaf(p, v0.z, acc[2]);
      acc[3] = fmaf(p, v0.w, acc[3]);
      acc[4] = fmaf(p, v1.x, acc[4]);
      acc[5] = fmaf(p, v1.y, acc[5]);
      acc[6] = fmaf(p, v1.z, acc[6]);
      acc[7] = fmaf(p, v1.w, acc[7]);
    }
    const float inv = 1.f / sum;
    float4 o0 = make_float4(acc[0]*inv, acc[1]*inv, acc[2]*inv, acc[3]*inv);
    float4 o1 = make_float4(acc[4]*inv, acc[5]*inv, acc[6]*inv, acc[7]*inv);
    *(float4*)&S[OFF_U + 3200 + h*400 + i*8]     = o0;
    *(float4*)&S[OFF_U + 3200 + h*400 + i*8 + 4] = o1;
  }
  __syncthreads();

  // ---- J: out = rawQ + ctx @ WO + bO (WO column loaded here, L1-hot) ----
  {
    float wo[32];
    load_wcol(WOg, d, wo);
    const int s0 = t >> 5;
    float acc[7];
    #pragma unroll
    for (int ss = 0; ss < 7; ++ss) acc[ss] = bo;
    #pragma unroll
    for (int kb = 0; kb < 32; kb += 4) {
      const int h = kb >> 3, k4 = kb & 4;
      #pragma unroll
      for (int ss = 0; ss < 7; ++ss) {
        const int s = s0 + ss*8;
        if (s < 50) {
          const float4 x = *(const float4*)&S[OFF_U + 3200 + h*400 + s*8 + k4];
          acc[ss] = fmaf(x.x, wo[kb+0], fmaf(x.y, wo[kb+1],
                    fmaf(x.z, wo[kb+2], fmaf(x.w, wo[kb+3], acc[ss]))));
        }
      }
    }
    #pragma unroll
    for (int ss = 0; ss < 7; ++ss) {
      const int s = s0 + ss*8;
      if (s < 50) outg[b*1600 + s*32 + d] = S[OFF_U + s*32 + d] + acc[ss];
    }
  }
}

extern "C" void kernel_launch(void* const* d_in, const int* in_sizes, int n_in,
                              void* d_out, int out_size, void* d_ws, size_t ws_size,
                              hipStream_t stream) {
  const float* Q  = (const float*)d_in[0];
  const float* K  = (const float*)d_in[1];
  const float* V  = (const float*)d_in[2];
  const void*  M  = d_in[3];
  const float* WQ = (const float*)d_in[4];
  const float* bQ = (const float*)d_in[5];
  const float* WK = (const float*)d_in[6];
  const float* bK = (const float*)d_in[7];
  const float* WV = (const float*)d_in[8];
  const float* bV = (const float*)d_in[9];
  const float* WO = (const float*)d_in[10];
  const float* bO = (const float*)d_in[11];
  float* out = (float*)d_out;
  (void)d_ws; (void)ws_size; (void)in_sizes; (void)n_in; (void)out_size;

  hipLaunchKernelGGL(mha, dim3(NB), dim3(256), 0, stream,
                     Q, K, V, M, WQ, bQ, WK, bK, WV, bV, WO, bO, out);
}

// Round 4
// 107.546 us; speedup vs baseline: 4.1064x; 4.1064x over previous
//
#include <hip/hip_runtime.h>

// B=4096, S=50, D=32, H=4, HD=8. One block per batch.
// Projections via bf16 MFMA 16x16x32 (K=32=D in one instruction), attention VALU f32.
#define NB 4096
constexpr float kScale = 0.35355339059327378f; // 1/sqrt(8)
constexpr float NEGBIG = -3.0e38f;             // finite -inf stand-in (avoids inf-inf NaN)

typedef __attribute__((ext_vector_type(8))) short bf16x8;  // 8 bf16 = 4 VGPRs
typedef __attribute__((ext_vector_type(4))) float f32x4;

__device__ __forceinline__ unsigned short f2bf(float f) {   // RNE f32->bf16
  unsigned u = __float_as_uint(f);
  return (unsigned short)((u + 0x7FFFu + ((u >> 16) & 1u)) >> 16);
}
__device__ __forceinline__ float bf2f(unsigned short h) {
  return __uint_as_float(((unsigned)h) << 16);
}

// LDS: tiles are [64 rows][40 bf16] (stride 40 => bank-quad 2-way alias = free; rows 16B aligned)
__global__ __launch_bounds__(256) void mha(
    const float* __restrict__ Qg, const float* __restrict__ Kg,
    const float* __restrict__ Vg, const void* __restrict__ maskg,
    const float* __restrict__ WQg, const float* __restrict__ bQg,
    const float* __restrict__ WKg, const float* __restrict__ bKg,
    const float* __restrict__ WVg, const float* __restrict__ bVg,
    const float* __restrict__ WOg, const float* __restrict__ bOg,
    float* __restrict__ outg)
{
  __shared__ __align__(16) short sT0[64*40];     // 5120 B  activation tile A
  __shared__ __align__(16) short sT1[64*40];     // 5120 B  activation tile B
  __shared__ __align__(16) short sWt[4*32*40];   // 10240 B W^T bf16: WQ|WK|WV|WO
  __shared__ __align__(16) float sKV[3200];      // 12800 B k2 [h][s][8] | v2 [h][s][8]
  __shared__ float sBias[128];                   // bQ|bK|bV|bO
  __shared__ unsigned sMask[104];                // 100 packed rows + flag at [100]
  // total ~34.2 KB -> 4 blocks/CU

  const int t = threadIdx.x;
  const int b = blockIdx.x;
  const int lane = t & 63;
  const int wv = t >> 6;              // wave id = M-tile index
  const int c = lane & 15, g = lane >> 4;

  auto stage_tile = [&](const float* __restrict__ src, short* dst) {
    #pragma unroll
    for (int it = 0; it < 2; ++it) {
      const int idx = t + it*256;
      if (idx < 400) {
        const float4 x = ((const float4*)src)[idx];
        const int s = idx >> 3, qd = idx & 7;
        const unsigned lo = (unsigned)f2bf(x.x) | ((unsigned)f2bf(x.y) << 16);
        const unsigned hi = (unsigned)f2bf(x.z) | ((unsigned)f2bf(x.w) << 16);
        *(uint2*)&dst[s*40 + qd*4] = make_uint2(lo, hi);
      }
    }
  };

  // D = A(tile) @ W(k,n from W^T rows) + bias; writes bf16 tile or f32 head-layout.
  auto mfma_pass = [&](const short* At, const short* Bt, int biasOff,
                       short* dstTile, float* dstF32, float scale, bool toF32) {
    const bf16x8 a = *(const bf16x8*)&At[(wv*16 + c)*40 + g*8];   // A[row=wv*16+c][k=g*8+e]
    #pragma unroll
    for (int Nj = 0; Nj < 2; ++Nj) {
      const bf16x8 bb = *(const bf16x8*)&Bt[(Nj*16 + c)*40 + g*8]; // B[k=g*8+e][n=Nj*16+c]
      const float bvv = sBias[biasOff + Nj*16 + c];
      f32x4 acc = {bvv, bvv, bvv, bvv};                            // bias folded into C
      acc = __builtin_amdgcn_mfma_f32_16x16x32_bf16(a, bb, acc, 0, 0, 0);
      #pragma unroll
      for (int r = 0; r < 4; ++r) {
        const int row = wv*16 + g*4 + r;      // verified C/D: col=lane&15, row=(lane>>4)*4+reg
        const int col = Nj*16 + c;
        const float v = acc[r] * scale;
        if (toF32) {
          if (row < 50) dstF32[(col >> 3)*400 + row*8 + (col & 7)] = v;  // [h][s][hd]
        } else {
          dstTile[row*40 + col] = (short)f2bf(v);
        }
      }
    }
  };

  // ---- A: stage rawK tile; W^T bf16 tiles; biases; zero pad rows; mask-width flag ----
  stage_tile(Kg + b*1600, sT0);
  {
    const float* Ws[4] = {WQg, WKg, WVg, WOg};
    #pragma unroll
    for (int m = 0; m < 4; ++m) {
      #pragma unroll
      for (int it = 0; it < 4; ++it) {
        const int idx = t + it*256;                 // 1024 elems, coalesced read
        const int k = idx >> 5, d = idx & 31;
        sWt[m*1280 + d*40 + k] = (short)f2bf(Ws[m][idx]);   // W^T[d][k]
      }
    }
    if      (t < 32)  sBias[t] = bQg[t];
    else if (t < 64)  sBias[t] = bKg[t-32];
    else if (t < 96)  sBias[t] = bVg[t-64];
    else if (t < 128) sBias[t] = bOg[t-96];
    if (t < 140) {    // zero rows 50..63 of both tiles once (finite-garbage guard)
      short* dst = (t < 70) ? sT0 : sT1;
      const int o = (t < 70) ? t : t - 70;
      *(uint4*)&dst[2000 + o*8] = make_uint4(0,0,0,0);
    }
    if (t < 64) {     // int32 vs byte mask detection
      const unsigned w = ((const unsigned*)maskg)[t];
      const unsigned long long ball = __ballot(w > 1u);
      if (t == 0) sMask[100] = (ball != 0ull) ? 1u : 0u;
    }
  }
  __syncthreads();

  // ---- B: bit-pack mask (t<100); pass1 K: sT0 @ WK -> sT1 ----
  {
    const unsigned flag = sMask[100];
    if (t < 100) {
      const int i = t >> 1, half = t & 1;
      const int base = b*2500 + i*50 + half*32;
      const int cnt = half ? 18 : 32;
      unsigned w = 0;
      if (flag) {
        const unsigned char* mp = (const unsigned char*)maskg + base;
        for (int e = 0; e < cnt; ++e) w |= (mp[e] != 0) ? (1u << e) : 0u;
      } else {
        const int* mp = (const int*)maskg + base;
        for (int e = 0; e < cnt; ++e) w |= (mp[e] != 0) ? (1u << e) : 0u;
      }
      sMask[t] = w;
    }
  }
  mfma_pass(sT0, sWt + 1280, 32, sT1, nullptr, 1.f, false);
  __syncthreads();

  // ---- C: pass2 K -> k2 f32; stage rawV -> sT0 ----
  mfma_pass(sT1, sWt + 1280, 32, nullptr, sKV, 1.f, true);
  stage_tile(Vg + b*1600, sT0);
  __syncthreads();

  // ---- D: pass1 V: sT0 @ WV -> sT1 ----
  mfma_pass(sT0, sWt + 2560, 64, sT1, nullptr, 1.f, false);
  __syncthreads();

  // ---- E: pass2 V -> v2 f32; stage rawQ -> sT0 ----
  mfma_pass(sT1, sWt + 2560, 64, nullptr, sKV + 1600, 1.f, true);
  stage_tile(Qg + b*1600, sT0);
  __syncthreads();

  // ---- F: pass1 Q: sT0 @ WQ -> sT1 ----
  mfma_pass(sT0, sWt + 0, 0, sT1, nullptr, 1.f, false);
  __syncthreads();

  // ---- G: pass2 Q (pre-scaled) -> q bf16 tile in sT0 ----
  mfma_pass(sT1, sWt + 0, 0, sT0, nullptr, kScale, false);
  __syncthreads();

  // ---- H: attention, 2 query rows per thread (t<100), online softmax; ctx -> sT1 ----
  if (t < 100) {
    const int h = t / 25, p = t - h*25;
    const int i0 = p, i1 = p + 25;
    const bf16x8 qav = *(const bf16x8*)&sT0[i0*40 + h*8];
    const bf16x8 qbv = *(const bf16x8*)&sT0[i1*40 + h*8];
    float qa[8], qb[8];
    #pragma unroll
    for (int e = 0; e < 8; ++e) {
      qa[e] = bf2f((unsigned short)qav[e]);
      qb[e] = bf2f((unsigned short)qbv[e]);
    }
    const unsigned a0 = sMask[i0*2], a1 = sMask[i0*2+1];
    const unsigned b0 = sMask[i1*2], b1 = sMask[i1*2+1];
    const float* kh = &sKV[h*400];
    const float* vh = &sKV[1600 + h*400];
    float ma = -1e30f, mb = -1e30f, sua = 0.f, sub = 0.f;
    float aa0=0,aa1=0,aa2=0,aa3=0,aa4=0,aa5=0,aa6=0,aa7=0;
    float ab0=0,ab1=0,ab2=0,ab3=0,ab4=0,ab5=0,ab6=0,ab7=0;
    for (int j = 0; j < 50; ++j) {
      const float4 k0 = *(const float4*)&kh[j*8];
      const float4 k1 = *(const float4*)&kh[j*8+4];
      const float4 v0 = *(const float4*)&vh[j*8];
      const float4 v1 = *(const float4*)&vh[j*8+4];
      const unsigned bitA = (j < 32) ? ((a0 >> j) & 1u) : ((a1 >> (j-32)) & 1u);
      const unsigned bitB = (j < 32) ? ((b0 >> j) & 1u) : ((b1 >> (j-32)) & 1u);
      // row i0
      float s = qa[0]*k0.x;
      s = fmaf(qa[1],k0.y,s); s = fmaf(qa[2],k0.z,s); s = fmaf(qa[3],k0.w,s);
      s = fmaf(qa[4],k1.x,s); s = fmaf(qa[5],k1.y,s); s = fmaf(qa[6],k1.z,s); s = fmaf(qa[7],k1.w,s);
      s = bitA ? NEGBIG : s;
      if (s > ma) {
        const float sc = __expf(ma - s); ma = s; sua *= sc;
        aa0*=sc; aa1*=sc; aa2*=sc; aa3*=sc; aa4*=sc; aa5*=sc; aa6*=sc; aa7*=sc;
      }
      const float pa = __expf(s - ma);
      sua += pa;
      aa0 = fmaf(pa,v0.x,aa0); aa1 = fmaf(pa,v0.y,aa1); aa2 = fmaf(pa,v0.z,aa2); aa3 = fmaf(pa,v0.w,aa3);
      aa4 = fmaf(pa,v1.x,aa4); aa5 = fmaf(pa,v1.y,aa5); aa6 = fmaf(pa,v1.z,aa6); aa7 = fmaf(pa,v1.w,aa7);
      // row i1
      float u = qb[0]*k0.x;
      u = fmaf(qb[1],k0.y,u); u = fmaf(qb[2],k0.z,u); u = fmaf(qb[3],k0.w,u);
      u = fmaf(qb[4],k1.x,u); u = fmaf(qb[5],k1.y,u); u = fmaf(qb[6],k1.z,u); u = fmaf(qb[7],k1.w,u);
      u = bitB ? NEGBIG : u;
      if (u > mb) {
        const float sc = __expf(mb - u); mb = u; sub *= sc;
        ab0*=sc; ab1*=sc; ab2*=sc; ab3*=sc; ab4*=sc; ab5*=sc; ab6*=sc; ab7*=sc;
      }
      const float pb = __expf(u - mb);
      sub += pb;
      ab0 = fmaf(pb,v0.x,ab0); ab1 = fmaf(pb,v0.y,ab1); ab2 = fmaf(pb,v0.z,ab2); ab3 = fmaf(pb,v0.w,ab3);
      ab4 = fmaf(pb,v1.x,ab4); ab5 = fmaf(pb,v1.y,ab5); ab6 = fmaf(pb,v1.z,ab6); ab7 = fmaf(pb,v1.w,ab7);
    }
    const float ia = 1.f / sua, ib = 1.f / sub;
    {
      const unsigned w0 = (unsigned)f2bf(aa0*ia) | ((unsigned)f2bf(aa1*ia) << 16);
      const unsigned w1 = (unsigned)f2bf(aa2*ia) | ((unsigned)f2bf(aa3*ia) << 16);
      const unsigned w2 = (unsigned)f2bf(aa4*ia) | ((unsigned)f2bf(aa5*ia) << 16);
      const unsigned w3 = (unsigned)f2bf(aa6*ia) | ((unsigned)f2bf(aa7*ia) << 16);
      *(uint4*)&sT1[i0*40 + h*8] = make_uint4(w0,w1,w2,w3);
    }
    {
      const unsigned w0 = (unsigned)f2bf(ab0*ib) | ((unsigned)f2bf(ab1*ib) << 16);
      const unsigned w1 = (unsigned)f2bf(ab2*ib) | ((unsigned)f2bf(ab3*ib) << 16);
      const unsigned w2 = (unsigned)f2bf(ab4*ib) | ((unsigned)f2bf(ab5*ib) << 16);
      const unsigned w3 = (unsigned)f2bf(ab6*ib) | ((unsigned)f2bf(ab7*ib) << 16);
      *(uint4*)&sT1[i1*40 + h*8] = make_uint4(w0,w1,w2,w3);
    }
  }
  __syncthreads();

  // ---- I: out = ctx @ WO + bO + Q (residual re-read from global, L1-hot) ----
  {
    const bf16x8 a = *(const bf16x8*)&sT1[(wv*16 + c)*40 + g*8];
    #pragma unroll
    for (int Nj = 0; Nj < 2; ++Nj) {
      const bf16x8 bb = *(const bf16x8*)&sWt[3840 + (Nj*16 + c)*40 + g*8];
      const float bvv = sBias[96 + Nj*16 + c];
      f32x4 acc = {bvv, bvv, bvv, bvv};
      acc = __builtin_amdgcn_mfma_f32_16x16x32_bf16(a, bb, acc, 0, 0, 0);
      #pragma unroll
      for (int r = 0; r < 4; ++r) {
        const int row = wv*16 + g*4 + r;
        const int col = Nj*16 + c;
        if (row < 50) {
          const int gi = b*1600 + row*32 + col;
          outg[gi] = acc[r] + Qg[gi];
        }
      }
    }
  }
}

extern "C" void kernel_launch(void* const* d_in, const int* in_sizes, int n_in,
                              void* d_out, int out_size, void* d_ws, size_t ws_size,
                              hipStream_t stream) {
  const float* Q  = (const float*)d_in[0];
  const float* K  = (const float*)d_in[1];
  const float* V  = (const float*)d_in[2];
  const void*  M  = d_in[3];
  const float* WQ = (const float*)d_in[4];
  const float* bQ = (const float*)d_in[5];
  const float* WK = (const float*)d_in[6];
  const float* bK = (const float*)d_in[7];
  const float* WV = (const float*)d_in[8];
  const float* bV = (const float*)d_in[9];
  const float* WO = (const float*)d_in[10];
  const float* bO = (const float*)d_in[11];
  float* out = (float*)d_out;
  (void)d_ws; (void)ws_size; (void)in_sizes; (void)n_in; (void)out_size;

  hipLaunchKernelGGL(mha, dim3(NB), dim3(256), 0, stream,
                     Q, K, V, M, WQ, bQ, WK, bK, WV, bV, WO, bO, out);
}